// Round 1
// 606.540 us; speedup vs baseline: 1.1238x; 1.1238x over previous
//
#include <hip/hip_runtime.h>

#define BB 512
#define TT 256
#define DD 512
#define HH 102
#define PP 51
#define NKEEP 128

typedef unsigned short u16;
typedef unsigned int u32;
typedef unsigned long long u64;
typedef float f32x4 __attribute__((ext_vector_type(4)));
typedef short s16x8 __attribute__((ext_vector_type(8)));

#define MFMA16(A, B, C) __builtin_amdgcn_mfma_f32_16x16x32_bf16((A), (B), (C), 0, 0, 0)

static __device__ __forceinline__ float bf2f(u16 u) {
  u32 v = ((u32)u) << 16;
  float f;
  __builtin_memcpy(&f, &v, 4);
  return f;
}
static __device__ __forceinline__ u16 f2bf(float f) {
  u32 v;
  __builtin_memcpy(&v, &f, 4);
  u32 r = v + 0x7fffu + ((v >> 16) & 1u);
  return (u16)(r >> 16);
}
// v_cvt_pk_bf16_f32: dst.lo = bf16(a), dst.hi = bf16(b)  (no builtin on gfx950)
static __device__ __forceinline__ u32 cvtpk(float a, float b) {
  u32 r;
  asm("v_cvt_pk_bf16_f32 %0, %1, %2" : "=v"(r) : "v"(a), "v"(b));
  return r;
}
static __device__ __forceinline__ float flo16(u32 u) {
  u32 v = u << 16;
  float f;
  __builtin_memcpy(&f, &v, 4);
  return f;
}
static __device__ __forceinline__ float fhi16(u32 u) {
  u32 v = u & 0xffff0000u;
  float f;
  __builtin_memcpy(&f, &v, 4);
  return f;
}
static __device__ __forceinline__ s16x8 mkfrag4(u32 a, u32 b, u32 c, u32 d) {
  u32 t[4] = {a, b, c, d};
  s16x8 f;
  __builtin_memcpy(&f, t, 16);
  return f;
}
static __device__ __forceinline__ s16x8 mkfrag2(u64 a, u64 b) {
  u64 t[2] = {a, b};
  s16x8 f;
  __builtin_memcpy(&f, t, 16);
  return f;
}
// hardware transpose read: each lane reads its own 8B, HW transposes 4x16 bf16
// tiles within each 16-lane group (lane gets column lane&15, rows j=0..3).
static __device__ __forceinline__ u64 trread(u32 addr, int imm) {
  u64 d;
  asm volatile("ds_read_b64_tr_b16 %0, %1 offset:%2" : "=v"(d) : "v"(addr), "i"(imm));
  return d;
}

// ---------------- Kernel 1: scores, sort, non-softmax, extra row, LN stats ----
// blocks >= BB: weight prep (bf16 hi/lo transposed W1, W2 into workspace)
__global__ __launch_bounds__(1024, 4) void k_score(
    const float* __restrict__ x, const float* __restrict__ ca,
    const float* __restrict__ w1, const float* __restrict__ w2,
    float* __restrict__ out, int* __restrict__ keepg,
    float* __restrict__ muk, float* __restrict__ ivk,
    u16* __restrict__ w1th, u16* __restrict__ w1tl,
    u16* __restrict__ w2th, u16* __restrict__ w2tl) {
  const int tid = threadIdx.x;

  if (blockIdx.x >= BB) {  // ---- weight prep: 16 blocks x 4096 elems ----
    const int e0 = (blockIdx.x - BB) * 4096;
#pragma unroll
    for (int i = 0; i < 4; ++i) {
      const int e = e0 + i * 1024 + tid;
      if (e < 57344) {  // W1T[112][512] = W1[k][p] pad p->112
        const int p = e >> 9, k = e & 511;
        const float v = (p < HH) ? w1[(size_t)k * HH + p] : 0.f;
        const u16 hi = f2bf(v);
        w1th[e] = hi;
        w1tl[e] = f2bf(v - bf2f(hi));
      } else {  // W2T[64][128] = W2[j][p] pad p->64, j->128
        const int e2 = e - 57344;
        const int p = e2 >> 7, j = e2 & 127;
        const float v = (p < PP && j < HH) ? w2[(size_t)j * PP + p] : 0.f;
        const u16 hi = f2bf(v);
        w2th[e2] = hi;
        w2tl[e2] = f2bf(v - bf2f(hi));
      }
    }
    return;
  }

  __shared__ float part[8 * 512];  // 16 KB; aliased as pc[] in phase 3
  __shared__ float glo[DD];
  __shared__ float sc[TT];
  __shared__ float ss[TT];
  __shared__ int perm[TT];
  __shared__ float wq[NKEEP];
  __shared__ float red[128];
  __shared__ float mls[TT], ils[TT];
  int* pc = (int*)part;

  const int b = blockIdx.x;
  const float* xb = x + (size_t)b * TT * DD;

  // phase 1: mean over tokens, 8-way token-split partials
  {
    int c4 = (tid & 127) * 4, tg = tid >> 7;
    float4 a = {0.f, 0.f, 0.f, 0.f};
    const float* p0 = xb + tg * 32 * DD + c4;
    for (int t = 0; t < 32; ++t) {
      float4 v = *(const float4*)(p0 + t * DD);
      a.x += v.x; a.y += v.y; a.z += v.z; a.w += v.w;
    }
    *(float4*)&part[tg * 512 + c4] = a;
  }
  __syncthreads();
  if (tid < 128) {
    int c4 = tid * 4;
    float4 m = {0.f, 0.f, 0.f, 0.f};
    for (int g = 0; g < 8; ++g) {
      float4 v = *(const float4*)&part[g * 512 + c4];
      m.x += v.x; m.y += v.y; m.z += v.z; m.w += v.w;
    }
    m.x *= (1.f / TT); m.y *= (1.f / TT); m.z *= (1.f / TT); m.w *= (1.f / TT);
    *(float4*)&glo[c4] = m;
    red[tid] = m.x * m.x + m.y * m.y + m.z * m.z + m.w * m.w;
  }
  __syncthreads();
  for (int s = 64; s > 0; s >>= 1) {
    if (tid < s) red[tid] += red[tid + s];
    __syncthreads();
  }
  if (tid < 128) {
    float inv = 1.f / fmaxf(sqrtf(red[0]), 1e-12f);
    int c4 = tid * 4;
    float4 m = *(float4*)&glo[c4];
    m.x *= inv; m.y *= inv; m.z *= inv; m.w *= inv;
    *(float4*)&glo[c4] = m;
  }
  __syncthreads();

  // phase 2: per-token scores + LN stats (16 waves x 16 tokens)
  {
    const int w = tid >> 6, lane = tid & 63;
    float gl[8];
#pragma unroll
    for (int j = 0; j < 8; ++j) gl[j] = glo[lane * 8 + j];
    for (int i = 0; i < 16; ++i) {
      int t = w * 16 + i;
      const float* xr = xb + t * DD + lane * 8;
      float4 r0 = *(const float4*)xr;
      float4 r1 = *(const float4*)(xr + 4);
      float vs[8] = {r0.x, r0.y, r0.z, r0.w, r1.x, r1.y, r1.z, r1.w};
      float s1 = 0.f, s2 = 0.f, dt = 0.f;
#pragma unroll
      for (int j = 0; j < 8; ++j) {
        s1 += vs[j];
        s2 += vs[j] * vs[j];
        dt += vs[j] * gl[j];
      }
      for (int m = 32; m; m >>= 1) {
        s1 += __shfl_xor(s1, m);
        s2 += __shfl_xor(s2, m);
        dt += __shfl_xor(dt, m);
      }
      if (lane == 0) {
        sc[t] = dt / fmaxf(sqrtf(s2), 1e-12f) + ca[b * TT + t];
        float mu = s1 * (1.f / DD);
        float var = s2 * (1.f / DD) - mu * mu;
        mls[t] = mu;
        ils[t] = rsqrtf(var + 1e-5f);
      }
    }
  }
  __syncthreads();

  // phase 3: stable descending rank, distributed over 4 j-chunks
  {
    int t = tid & 255, ch = tid >> 8;
    float st = sc[t];
    int cnt = 0;
    for (int j = ch * 64; j < ch * 64 + 64; ++j) {
      float sj = sc[j];
      cnt += (sj > st) || (sj == st && j < t);
    }
    pc[ch * 256 + t] = cnt;
  }
  __syncthreads();
  if (tid < 256) {
    int rank = pc[tid] + pc[256 + tid] + pc[512 + tid] + pc[768 + tid];
    perm[rank] = tid;
    ss[rank] = sc[tid];
  }
  __syncthreads();

  // phase 4: softmax over non-kept (sorted 128..255); max = ss[128] (sorted)
  if (tid < 128) {
    float e = expf(ss[NKEEP + tid] - ss[NKEEP]);
    wq[tid] = e;
    red[tid] = e;
  }
  __syncthreads();
  for (int s = 64; s > 0; s >>= 1) {
    if (tid < s) red[tid] += red[tid + s];
    __syncthreads();
  }
  if (tid < 128) {
    wq[tid] *= (1.f / red[0]);
    const int pm = perm[tid];
    keepg[b * NKEEP + tid] = pm;
    muk[b * NKEEP + tid] = mls[pm];
    ivk[b * NKEEP + tid] = ils[pm];
  }
  __syncthreads();

  // phase 5: extra = sum(non * w) -> out row 51 (8-way token-split)
  {
    int c4 = (tid & 127) * 4, tg = tid >> 7;
    float4 a = {0.f, 0.f, 0.f, 0.f};
    for (int q = tg * 16; q < tg * 16 + 16; ++q) {
      int tok = perm[NKEEP + q] & 255;
      float w = wq[q];
      float4 v = *(const float4*)(xb + tok * DD + c4);
      a.x += w * v.x; a.y += w * v.y; a.z += w * v.z; a.w += w * v.w;
    }
    *(float4*)&part[tg * 512 + c4] = a;
  }
  __syncthreads();
  if (tid < 128) {
    int c4 = tid * 4;
    float4 m = {0.f, 0.f, 0.f, 0.f};
    for (int g = 0; g < 8; ++g) {
      float4 v = *(const float4*)&part[g * 512 + c4];
      m.x += v.x; m.y += v.y; m.z += v.z; m.w += v.w;
    }
    *(float4*)(out + ((size_t)b * 52 + 51) * DD + c4) = m;
  }
}

// ------ Kernel 2 (MFMA): LN -> GEMM1 -> GELU -> GEMM2 -> softmax -> aggr ----
// 8 waves. mm1: wave w owns token tile 16w..16w+15 (A from global+LN in regs,
// B from L2-resident bf16 W1T hi/lo; 3-term split => ~f32 accuracy).
// mm2: h (single bf16, as before) via swizzled LDS; W2T hi/lo global.
// aggr: w hi/lo A-frags from wt; sel hi/lo staged per-64-col chunk into
// ds_read_b64_tr_b16 tile layout (B-frags via HW transpose).
__global__ __launch_bounds__(512, 4) void k_fused(
    const float* __restrict__ x,
    const u16* __restrict__ w1th, const u16* __restrict__ w1tl,
    const u16* __restrict__ w2th, const u16* __restrict__ w2tl,
    const float* __restrict__ lng, const float* __restrict__ lnb,
    const float* __restrict__ b1, const float* __restrict__ b2,
    const float* __restrict__ scale, const int* __restrict__ keepg,
    const float* __restrict__ mukg, const float* __restrict__ ivkg,
    float* __restrict__ out) {
  __shared__ __align__(16) char SEL[32768];     // h[128][128]bf16 swz | sel tr-tiles hi/lo
  __shared__ __align__(16) float wt[64 * 132];  // logits/softmax, rows 51..63 = 0
  __shared__ __align__(16) float lnGs[DD], lnBs[DD];
  __shared__ float mus[NKEEP], ivs[NKEEP];
  __shared__ int keeps[NKEEP];
  __shared__ float b1s[112], b2s[64];
  __shared__ float sscale;

  const int b = blockIdx.x;
  const int tid = threadIdx.x;
  const int w = tid >> 6;       // wave 0..7
  const int lane = tid & 63;
  const int cl = lane & 15;     // 16-lane column index
  const int g2 = lane >> 4;     // quarter-group 0..3

  if (tid < NKEEP) {
    keeps[tid] = keepg[b * NKEEP + tid] & 255;
    mus[tid] = mukg[b * NKEEP + tid];
    ivs[tid] = ivkg[b * NKEEP + tid];
  }
  for (int i = tid; i < DD; i += 512) {
    lnGs[i] = lng[i];
    lnBs[i] = lnb[i];
  }
  if (tid < 112) b1s[tid] = (tid < HH) ? b1[tid] : 0.f;
  if (tid < 64) b2s[tid] = (tid < PP) ? b2[tid] : 0.f;
  if (tid == 0) sscale = scale[0];
  __syncthreads();

  const float* xb = x + (size_t)b * TT * DD;

  // ---- mm1: h[128][112] = LN(sel)[128][512] @ W1[512][112] ----
  const int rowm = 16 * w + cl;
  const int tok = keeps[rowm];
  const float mu = mus[rowm], iv = ivs[rowm];
  const float nmuiv = -mu * iv;
  const float* xrow = xb + (size_t)tok * DD;

  f32x4 acc1[7];
#pragma unroll
  for (int n = 0; n < 7; ++n) acc1[n] = (f32x4){0.f, 0.f, 0.f, 0.f};

#pragma unroll 4
  for (int kk = 0; kk < 16; ++kk) {
    const int d0 = kk * 32 + g2 * 8;
    float4 xv0 = *(const float4*)(xrow + d0);
    float4 xv1 = *(const float4*)(xrow + d0 + 4);
    float4 gg0 = *(const float4*)&lnGs[d0];
    float4 gg1 = *(const float4*)&lnGs[d0 + 4];
    float4 bb0 = *(const float4*)&lnBs[d0];
    float4 bb1 = *(const float4*)&lnBs[d0 + 4];
    float y0 = fmaf(fmaf(xv0.x, iv, nmuiv), gg0.x, bb0.x);
    float y1 = fmaf(fmaf(xv0.y, iv, nmuiv), gg0.y, bb0.y);
    float y2 = fmaf(fmaf(xv0.z, iv, nmuiv), gg0.z, bb0.z);
    float y3 = fmaf(fmaf(xv0.w, iv, nmuiv), gg0.w, bb0.w);
    float y4 = fmaf(fmaf(xv1.x, iv, nmuiv), gg1.x, bb1.x);
    float y5 = fmaf(fmaf(xv1.y, iv, nmuiv), gg1.y, bb1.y);
    float y6 = fmaf(fmaf(xv1.z, iv, nmuiv), gg1.z, bb1.z);
    float y7 = fmaf(fmaf(xv1.w, iv, nmuiv), gg1.w, bb1.w);
    u32 h01 = cvtpk(y0, y1), h23 = cvtpk(y2, y3);
    u32 h45 = cvtpk(y4, y5), h67 = cvtpk(y6, y7);
    u32 l01 = cvtpk(y0 - flo16(h01), y1 - fhi16(h01));
    u32 l23 = cvtpk(y2 - flo16(h23), y3 - fhi16(h23));
    u32 l45 = cvtpk(y4 - flo16(h45), y5 - fhi16(h45));
    u32 l67 = cvtpk(y6 - flo16(h67), y7 - fhi16(h67));
    const s16x8 fh = mkfrag4(h01, h23, h45, h67);
    const s16x8 fl = mkfrag4(l01, l23, l45, l67);
    const int bcol = cl * 512 + d0;
#pragma unroll
    for (int n = 0; n < 7; ++n) {
      const s16x8 bh = *(const s16x8*)(w1th + n * 8192 + bcol);
      const s16x8 bl = *(const s16x8*)(w1tl + n * 8192 + bcol);
      acc1[n] = MFMA16(fh, bh, acc1[n]);
      acc1[n] = MFMA16(fl, bh, acc1[n]);
      acc1[n] = MFMA16(fh, bl, acc1[n]);
    }
  }

  // ---- bias + exact GELU -> h bf16 to swizzled LDS [128][128] ----
#pragma unroll
  for (int n = 0; n < 7; ++n) {
    const int col = 16 * n + cl;
    const float bia = b1s[col];
#pragma unroll
    for (int r = 0; r < 4; ++r) {
      const int row = 16 * w + 4 * g2 + r;
      float v = acc1[n][r] + bia;
      float ge = 0.5f * v * (1.f + erff(v * 0.70710678118f));
      const int byteoff = (row * 256 + col * 2) ^ ((row & 7) << 4);
      *(u16*)(SEL + byteoff) = f2bf(ge);
    }
  }
  for (int i = tid; i < 1024; i += 512) {  // zero pad cols 112..127
    const int row = i >> 3;
    const int col = 112 + 2 * (i & 7);
    const int byteoff = (row * 256 + col * 2) ^ ((row & 7) << 4);
    *(u32*)(SEL + byteoff) = 0u;
  }
  __syncthreads();

  // ---- mm2: logits[128][64] = h[128][128] @ W2T^T ----
  f32x4 acc2[4];
#pragma unroll
  for (int n = 0; n < 4; ++n) acc2[n] = (f32x4){0.f, 0.f, 0.f, 0.f};
  {
    const int row2 = 16 * w + cl;
#pragma unroll
    for (int kk = 0; kk < 4; ++kk) {
      const int byteoff = (row2 * 256 + kk * 64 + g2 * 16) ^ ((row2 & 7) << 4);
      const s16x8 ha = *(const s16x8*)(SEL + byteoff);
      const int bcol2 = cl * 128 + kk * 32 + g2 * 8;
#pragma unroll
      for (int n = 0; n < 4; ++n) {
        const s16x8 bh = *(const s16x8*)(w2th + n * 2048 + bcol2);
        const s16x8 bl = *(const s16x8*)(w2tl + n * 2048 + bcol2);
        acc2[n] = MFMA16(ha, bh, acc2[n]);
        acc2[n] = MFMA16(ha, bl, acc2[n]);
      }
    }
  }
  {
    const float scv = sscale;
#pragma unroll
    for (int n = 0; n < 4; ++n) {
      const int p = 16 * n + cl;
#pragma unroll
      for (int r = 0; r < 4; ++r) {
        const int k = 16 * w + 4 * g2 + r;
        wt[p * 132 + k] = (acc2[n][r] + b2s[p]) * scv;
      }
    }
  }
  __syncthreads();

  // ---- softmax over k (128) for each p (8 waves) ----
  for (int p = w; p < PP; p += 8) {
    float v0 = wt[p * 132 + lane], v1 = wt[p * 132 + 64 + lane];
    float mx = fmaxf(v0, v1);
    for (int m = 32; m; m >>= 1) mx = fmaxf(mx, __shfl_xor(mx, m));
    float e0 = expf(v0 - mx), e1 = expf(v1 - mx);
    float s = e0 + e1;
    for (int m = 32; m; m >>= 1) s += __shfl_xor(s, m);
    float is = 1.f / s;
    wt[p * 132 + lane] = e0 * is;
    wt[p * 132 + 64 + lane] = e1 * is;
  }
  __syncthreads();

  // ---- aggr: out[p][c] = w[p][k] @ sel[k][c], MFMA over 8 chunks of 64 cols ----
  const int mb = w >> 2;   // 0..1 -> rows 32*mb + {0..31}
  const int nsub = w & 3;  // 16-col tile within 64-col chunk
  s16x8 ah0[4], al0[4], ah1[4], al1[4];  // A-frags (w hi/lo), mi = 0,1
  {
    const int pr0 = 32 * mb + cl;
    const int pr1 = pr0 + 16;
#pragma unroll
    for (int kk = 0; kk < 4; ++kk) {
      f32x4 wa = *(const f32x4*)&wt[pr0 * 132 + kk * 32 + 8 * g2];
      f32x4 wb = *(const f32x4*)&wt[pr0 * 132 + kk * 32 + 8 * g2 + 4];
      u32 a0 = cvtpk(wa.x, wa.y), a1 = cvtpk(wa.z, wa.w);
      u32 a2 = cvtpk(wb.x, wb.y), a3 = cvtpk(wb.z, wb.w);
      ah0[kk] = mkfrag4(a0, a1, a2, a3);
      al0[kk] = mkfrag4(cvtpk(wa.x - flo16(a0), wa.y - fhi16(a0)),
                        cvtpk(wa.z - flo16(a1), wa.w - fhi16(a1)),
                        cvtpk(wb.x - flo16(a2), wb.y - fhi16(a2)),
                        cvtpk(wb.z - flo16(a3), wb.w - fhi16(a3)));
      f32x4 wc = *(const f32x4*)&wt[pr1 * 132 + kk * 32 + 8 * g2];
      f32x4 wd = *(const f32x4*)&wt[pr1 * 132 + kk * 32 + 8 * g2 + 4];
      u32 c0 = cvtpk(wc.x, wc.y), c1 = cvtpk(wc.z, wc.w);
      u32 c2 = cvtpk(wd.x, wd.y), c3 = cvtpk(wd.z, wd.w);
      ah1[kk] = mkfrag4(c0, c1, c2, c3);
      al1[kk] = mkfrag4(cvtpk(wc.x - flo16(c0), wc.y - fhi16(c0)),
                        cvtpk(wc.z - flo16(c1), wc.w - fhi16(c1)),
                        cvtpk(wd.x - flo16(c2), wd.y - fhi16(c2)),
                        cvtpk(wd.z - flo16(c3), wd.w - fhi16(c3)));
    }
  }
  const u32 trbase = (u32)(size_t)SEL + nsub * 1024 + g2 * 128 + 8 * cl;

  for (int ch = 0; ch < 8; ++ch) {
    const int cbase = ch * 64;
    // stage sel chunk (hi @0, lo @16384) in tr-tile layout:
    // tile(kk,nsub,wsel,g)=512B base, elem (r,c) at r*32 + c*2; k = 8g+4*wsel+r
#pragma unroll
    for (int s = 0; s < 4; ++s) {
      const int u = tid + s * 512;
      const int k = u >> 4, c4g = u & 15;
      const float4 v = *(const float4*)(xb + (size_t)keeps[k] * DD + cbase + 4 * c4g);
      u32 h01 = cvtpk(v.x, v.y), h23 = cvtpk(v.z, v.w);
      u32 q01 = cvtpk(v.x - flo16(h01), v.y - fhi16(h01));
      u32 q23 = cvtpk(v.z - flo16(h23), v.w - fhi16(h23));
      const int kl = k & 31;
      const int boff = ((k >> 5) * 8 + (c4g >> 2) * 2 + ((kl >> 2) & 1)) * 512 +
                       (kl >> 3) * 128 + (kl & 3) * 32 + (c4g & 3) * 8;
      *(u64*)(SEL + boff) = ((u64)h23 << 32) | h01;
      *(u64*)(SEL + 16384 + boff) = ((u64)q23 << 32) | q01;
    }
    __syncthreads();

    f32x4 acg0 = (f32x4){0.f, 0.f, 0.f, 0.f};
    f32x4 acg1 = (f32x4){0.f, 0.f, 0.f, 0.f};
    u64 th[4][2], tl[4][2];
#pragma unroll
    for (int kk = 0; kk < 4; ++kk) {
      th[kk][0] = trread(trbase, kk * 4096);
      th[kk][1] = trread(trbase, kk * 4096 + 512);
      tl[kk][0] = trread(trbase, kk * 4096 + 16384);
      tl[kk][1] = trread(trbase, kk * 4096 + 16896);
    }
    asm volatile("s_waitcnt lgkmcnt(0)" ::: "memory");
    __builtin_amdgcn_sched_barrier(0);
#pragma unroll
    for (int kk = 0; kk < 4; ++kk) {
      const s16x8 bh = mkfrag2(th[kk][0], th[kk][1]);
      const s16x8 bl = mkfrag2(tl[kk][0], tl[kk][1]);
      acg0 = MFMA16(ah0[kk], bh, acg0);
      acg0 = MFMA16(al0[kk], bh, acg0);
      acg0 = MFMA16(ah0[kk], bl, acg0);
      acg1 = MFMA16(ah1[kk], bh, acg1);
      acg1 = MFMA16(al1[kk], bh, acg1);
      acg1 = MFMA16(ah1[kk], bl, acg1);
    }
    const int ccol = cbase + 16 * nsub + cl;
#pragma unroll
    for (int r = 0; r < 4; ++r) {
      const int p0 = 32 * mb + 4 * g2 + r;
      if (p0 < PP) out[((size_t)b * 52 + p0) * DD + ccol] = acg0[r];
      const int p1 = 32 * mb + 16 + 4 * g2 + r;
      if (p1 < PP) out[((size_t)b * 52 + p1) * DD + ccol] = acg1[r];
    }
    __syncthreads();
  }
}

extern "C" void kernel_launch(void* const* d_in, const int* in_sizes, int n_in,
                              void* d_out, int out_size, void* d_ws, size_t ws_size,
                              hipStream_t stream) {
  const float* x = (const float*)d_in[0];
  const float* ca = (const float*)d_in[1];
  const float* lng = (const float*)d_in[2];
  const float* lnb = (const float*)d_in[3];
  const float* w1 = (const float*)d_in[4];
  const float* b1 = (const float*)d_in[5];
  const float* w2 = (const float*)d_in[6];
  const float* b2 = (const float*)d_in[7];
  const float* scale = (const float*)d_in[8];
  float* out = (float*)d_out;

  char* ws = (char*)d_ws;
  int* keepg = (int*)ws;                    // 512*128*4 = 262144
  float* muk = (float*)(ws + 262144);       // 262144
  float* ivk = (float*)(ws + 524288);       // 262144
  u16* w1th = (u16*)(ws + 786432);          // 114688
  u16* w1tl = (u16*)(ws + 901120);          // 114688
  u16* w2th = (u16*)(ws + 1015808);         // 16384
  u16* w2tl = (u16*)(ws + 1032192);         // 16384 -> total 1 MB

  k_score<<<BB + 16, 1024, 0, stream>>>(x, ca, w1, w2, out, keepg, muk, ivk,
                                        w1th, w1tl, w2th, w2tl);
  k_fused<<<BB, 512, 0, stream>>>(x, w1th, w1tl, w2th, w2tl, lng, lnb, b1, b2,
                                  scale, keepg, muk, ivk, out);
}

// Round 2
// 523.197 us; speedup vs baseline: 1.3028x; 1.1593x over previous
//
#include <hip/hip_runtime.h>

#define BB 512
#define TT 256
#define DD 512
#define HH 102
#define PP 51
#define NKEEP 128

typedef unsigned short u16;
typedef unsigned int u32;
typedef unsigned long long u64;
typedef float f32x4 __attribute__((ext_vector_type(4)));
typedef short s16x8 __attribute__((ext_vector_type(8)));

#define MFMA16(A, B, C) __builtin_amdgcn_mfma_f32_16x16x32_bf16((A), (B), (C), 0, 0, 0)

// async global->LDS, 16B per lane, dest = uniform base + lane*16
#define GLOAD16(gsrc, ldst)                                                     \
  __builtin_amdgcn_global_load_lds(                                             \
      (const __attribute__((address_space(1))) u32*)(gsrc),                     \
      (__attribute__((address_space(3))) u32*)(ldst), 16, 0, 0)

static __device__ __forceinline__ float bf2f(u16 u) {
  u32 v = ((u32)u) << 16;
  float f;
  __builtin_memcpy(&f, &v, 4);
  return f;
}
static __device__ __forceinline__ u16 f2bf(float f) {
  u32 v;
  __builtin_memcpy(&v, &f, 4);
  u32 r = v + 0x7fffu + ((v >> 16) & 1u);
  return (u16)(r >> 16);
}
// v_cvt_pk_bf16_f32: dst.lo = bf16(a), dst.hi = bf16(b)  (no builtin on gfx950)
static __device__ __forceinline__ u32 cvtpk(float a, float b) {
  u32 r;
  asm("v_cvt_pk_bf16_f32 %0, %1, %2" : "=v"(r) : "v"(a), "v"(b));
  return r;
}
static __device__ __forceinline__ float flo16(u32 u) {
  u32 v = u << 16;
  float f;
  __builtin_memcpy(&f, &v, 4);
  return f;
}
static __device__ __forceinline__ float fhi16(u32 u) {
  u32 v = u & 0xffff0000u;
  float f;
  __builtin_memcpy(&f, &v, 4);
  return f;
}
static __device__ __forceinline__ s16x8 mkfrag4(u32 a, u32 b, u32 c, u32 d) {
  u32 t[4] = {a, b, c, d};
  s16x8 f;
  __builtin_memcpy(&f, t, 16);
  return f;
}
static __device__ __forceinline__ s16x8 mkfrag2(u64 a, u64 b) {
  u64 t[2] = {a, b};
  s16x8 f;
  __builtin_memcpy(&f, t, 16);
  return f;
}
static __device__ __forceinline__ u64 trread(u32 addr, int imm) {
  u64 d;
  asm volatile("ds_read_b64_tr_b16 %0, %1 offset:%2" : "=v"(d) : "v"(addr), "i"(imm));
  return d;
}

// ---------------- Kernel 1: scores, sort, non-softmax, extra row, LN stats ----
// blocks >= BB: weight prep (bf16 hi/lo transposed W1, W2 into workspace)
__global__ __launch_bounds__(1024, 8) void k_score(
    const float* __restrict__ x, const float* __restrict__ ca,
    const float* __restrict__ w1, const float* __restrict__ w2,
    float* __restrict__ out, int* __restrict__ keepg,
    float* __restrict__ muk, float* __restrict__ ivk,
    u16* __restrict__ w1th, u16* __restrict__ w1tl,
    u16* __restrict__ w2th, u16* __restrict__ w2tl) {
  const int tid = threadIdx.x;

  if (blockIdx.x >= BB) {  // ---- weight prep: 16 blocks x 4096 elems ----
    const int e0 = (blockIdx.x - BB) * 4096;
#pragma unroll
    for (int i = 0; i < 4; ++i) {
      const int e = e0 + i * 1024 + tid;
      if (e < 57344) {  // W1T[112][512] = W1[k][p] pad p->112
        const int p = e >> 9, k = e & 511;
        const float v = (p < HH) ? w1[(size_t)k * HH + p] : 0.f;
        const u16 hi = f2bf(v);
        w1th[e] = hi;
        w1tl[e] = f2bf(v - bf2f(hi));
      } else {  // W2T[64][128] = W2[j][p] pad p->64, j->128
        const int e2 = e - 57344;
        const int p = e2 >> 7, j = e2 & 127;
        const float v = (p < PP && j < HH) ? w2[(size_t)j * PP + p] : 0.f;
        const u16 hi = f2bf(v);
        w2th[e2] = hi;
        w2tl[e2] = f2bf(v - bf2f(hi));
      }
    }
    return;
  }

  __shared__ float part[8 * 512];  // 16 KB; aliased as pc[] in phase 3
  __shared__ float glo[DD];
  __shared__ float sc[TT];
  __shared__ float ss[TT];
  __shared__ int perm[TT];
  __shared__ float wq[NKEEP];
  __shared__ float red[128];
  __shared__ float mls[TT], ils[TT];
  int* pc = (int*)part;

  const int b = blockIdx.x;
  const float* xb = x + (size_t)b * TT * DD;

  // phase 1: mean over tokens, 8-way token-split partials
  {
    int c4 = (tid & 127) * 4, tg = tid >> 7;
    float4 a = {0.f, 0.f, 0.f, 0.f};
    const float* p0 = xb + tg * 32 * DD + c4;
    for (int t = 0; t < 32; ++t) {
      float4 v = *(const float4*)(p0 + t * DD);
      a.x += v.x; a.y += v.y; a.z += v.z; a.w += v.w;
    }
    *(float4*)&part[tg * 512 + c4] = a;
  }
  __syncthreads();
  if (tid < 128) {
    int c4 = tid * 4;
    float4 m = {0.f, 0.f, 0.f, 0.f};
    for (int g = 0; g < 8; ++g) {
      float4 v = *(const float4*)&part[g * 512 + c4];
      m.x += v.x; m.y += v.y; m.z += v.z; m.w += v.w;
    }
    m.x *= (1.f / TT); m.y *= (1.f / TT); m.z *= (1.f / TT); m.w *= (1.f / TT);
    *(float4*)&glo[c4] = m;
    red[tid] = m.x * m.x + m.y * m.y + m.z * m.z + m.w * m.w;
  }
  __syncthreads();
  for (int s = 64; s > 0; s >>= 1) {
    if (tid < s) red[tid] += red[tid + s];
    __syncthreads();
  }
  if (tid < 128) {
    float inv = 1.f / fmaxf(sqrtf(red[0]), 1e-12f);
    int c4 = tid * 4;
    float4 m = *(float4*)&glo[c4];
    m.x *= inv; m.y *= inv; m.z *= inv; m.w *= inv;
    *(float4*)&glo[c4] = m;
  }
  __syncthreads();

  // phase 2: per-token scores + LN stats (16 waves x 16 tokens)
  {
    const int w = tid >> 6, lane = tid & 63;
    float gl[8];
#pragma unroll
    for (int j = 0; j < 8; ++j) gl[j] = glo[lane * 8 + j];
    for (int i = 0; i < 16; ++i) {
      int t = w * 16 + i;
      const float* xr = xb + t * DD + lane * 8;
      float4 r0 = *(const float4*)xr;
      float4 r1 = *(const float4*)(xr + 4);
      float vs[8] = {r0.x, r0.y, r0.z, r0.w, r1.x, r1.y, r1.z, r1.w};
      float s1 = 0.f, s2 = 0.f, dt = 0.f;
#pragma unroll
      for (int j = 0; j < 8; ++j) {
        s1 += vs[j];
        s2 += vs[j] * vs[j];
        dt += vs[j] * gl[j];
      }
      for (int m = 32; m; m >>= 1) {
        s1 += __shfl_xor(s1, m);
        s2 += __shfl_xor(s2, m);
        dt += __shfl_xor(dt, m);
      }
      if (lane == 0) {
        sc[t] = dt / fmaxf(sqrtf(s2), 1e-12f) + ca[b * TT + t];
        float mu = s1 * (1.f / DD);
        float var = s2 * (1.f / DD) - mu * mu;
        mls[t] = mu;
        ils[t] = rsqrtf(var + 1e-5f);
      }
    }
  }
  __syncthreads();

  // phase 3: stable descending rank, distributed over 4 j-chunks
  {
    int t = tid & 255, ch = tid >> 8;
    float st = sc[t];
    int cnt = 0;
    for (int j = ch * 64; j < ch * 64 + 64; ++j) {
      float sj = sc[j];
      cnt += (sj > st) || (sj == st && j < t);
    }
    pc[ch * 256 + t] = cnt;
  }
  __syncthreads();
  if (tid < 256) {
    int rank = pc[tid] + pc[256 + tid] + pc[512 + tid] + pc[768 + tid];
    perm[rank] = tid;
    ss[rank] = sc[tid];
  }
  __syncthreads();

  // phase 4: softmax over non-kept (sorted 128..255); max = ss[128] (sorted)
  if (tid < 128) {
    float e = expf(ss[NKEEP + tid] - ss[NKEEP]);
    wq[tid] = e;
    red[tid] = e;
  }
  __syncthreads();
  for (int s = 64; s > 0; s >>= 1) {
    if (tid < s) red[tid] += red[tid + s];
    __syncthreads();
  }
  if (tid < 128) {
    wq[tid] *= (1.f / red[0]);
    const int pm = perm[tid];
    keepg[b * NKEEP + tid] = pm;
    muk[b * NKEEP + tid] = mls[pm];
    ivk[b * NKEEP + tid] = ils[pm];
  }
  __syncthreads();

  // phase 5: extra = sum(non * w) -> out row 51 (8-way token-split)
  {
    int c4 = (tid & 127) * 4, tg = tid >> 7;
    float4 a = {0.f, 0.f, 0.f, 0.f};
    for (int q = tg * 16; q < tg * 16 + 16; ++q) {
      int tok = perm[NKEEP + q] & 255;
      float w = wq[q];
      float4 v = *(const float4*)(xb + tok * DD + c4);
      a.x += w * v.x; a.y += w * v.y; a.z += w * v.z; a.w += w * v.w;
    }
    *(float4*)&part[tg * 512 + c4] = a;
  }
  __syncthreads();
  if (tid < 128) {
    int c4 = tid * 4;
    float4 m = {0.f, 0.f, 0.f, 0.f};
    for (int g = 0; g < 8; ++g) {
      float4 v = *(const float4*)&part[g * 512 + c4];
      m.x += v.x; m.y += v.y; m.z += v.z; m.w += v.w;
    }
    *(float4*)(out + ((size_t)b * 52 + 51) * DD + c4) = m;
  }
}

// ------ Kernel 2 (MFMA): LN -> GEMM1 -> GELU -> GEMM2 -> softmax -> aggr ----
// LDS pool phases:
//  mm1 : WB[2] double-buffer @0, each 28672 B (W1T tile hi 14336 | lo 14336)
//  mm2 : SEL h-tile [128][128]bf16 swz @0 (32768) | W2 tiles @32768 (hi16K|lo16K)
//  aggr: SEL tr-tiles hi @0 / lo @16384 | wt[64][132] f32 @32768 (33792)
__global__ __launch_bounds__(512, 2) void k_fused(
    const float* __restrict__ x,
    const u16* __restrict__ w1th, const u16* __restrict__ w1tl,
    const u16* __restrict__ w2th, const u16* __restrict__ w2tl,
    const float* __restrict__ lng, const float* __restrict__ lnb,
    const float* __restrict__ b1, const float* __restrict__ b2,
    const float* __restrict__ scale, const int* __restrict__ keepg,
    const float* __restrict__ mukg, const float* __restrict__ ivkg,
    float* __restrict__ out) {
  __shared__ __align__(16) char pool[66560];
  __shared__ __align__(16) float lnGs[DD], lnBs[DD];
  __shared__ float mus[NKEEP], ivs[NKEEP];
  __shared__ int keeps[NKEEP];
  __shared__ float b1s[112], b2s[64];
  __shared__ float sscale;

  const int b = blockIdx.x;
  const int tid = threadIdx.x;
  const int w = tid >> 6;    // wave 0..7
  const int lane = tid & 63;
  const int cl = lane & 15;  // 16-lane column index
  const int g2 = lane >> 4;  // quarter-group 0..3

  if (tid < NKEEP) {
    keeps[tid] = keepg[b * NKEEP + tid] & 255;
    mus[tid] = mukg[b * NKEEP + tid];
    ivs[tid] = ivkg[b * NKEEP + tid];
  }
  for (int i = tid; i < DD; i += 512) {
    lnGs[i] = lng[i];
    lnBs[i] = lnb[i];
  }
  if (tid < 112) b1s[tid] = (tid < HH) ? b1[tid] : 0.f;
  if (tid < 64) b2s[tid] = (tid < PP) ? b2[tid] : 0.f;
  if (tid == 0) sscale = scale[0];
  __syncthreads();

  const float* xb = x + (size_t)b * TT * DD;

  // ================= mm1: h[128][112] = LN(sel) @ W1 =================
  const int rowm = 16 * w + cl;
  const int tok = keeps[rowm];
  const float mu = mus[rowm], iv = ivs[rowm];
  const float nmuiv = -mu * iv;
  const float* xrow = xb + (size_t)tok * DD;

  // per-thread swizzled LDS byte offsets for B-frag reads (row = n*16+cl):
  // byte = n*2048 + cl*128 + ((kh*4+g2)^(cl&7))*16   (+14336 for lo)
  const int swz7 = cl & 7;
  const int bA0 = cl * 128 + ((g2 ^ swz7) << 4);
  const int bA1 = cl * 128 + (((4 + g2) ^ swz7) << 4);

  f32x4 acc1[7];
#pragma unroll
  for (int n = 0; n < 7; ++n) acc1[n] = (f32x4){0.f, 0.f, 0.f, 0.f};

  // stage W1T tile tt (hi+lo 28672 B) into dst; source pre-swizzled so the
  // linear LDS slot (row,u) holds global unit u^(row&7)  [m173 pattern]
#define STAGE_W1(tt, dst)                                                      \
  {                                                                            \
    _Pragma("unroll") for (int i_ = 0; i_ < 4; ++i_) {                         \
      const int j_ = w + 8 * i_;                                               \
      if (j_ < 28) {                                                           \
        const int s_ = j_ * 64 + lane;                                         \
        const int part_ = (j_ >= 14);                                          \
        const int sr_ = s_ - part_ * 896;                                      \
        const int row_ = sr_ >> 3, uu_ = sr_ & 7;                              \
        const u16* src_ = (part_ ? w1tl : w1th) + row_ * 512 + (tt)*64 +       \
                          ((uu_ ^ (row_ & 7)) << 3);                           \
        GLOAD16(src_, (dst) + j_ * 1024);                                      \
      }                                                                        \
    }                                                                          \
  }

  float4 xc0 = *(const float4*)(xrow + g2 * 8);
  float4 xc1 = *(const float4*)(xrow + g2 * 8 + 4);
  float4 xc2 = *(const float4*)(xrow + 32 + g2 * 8);
  float4 xc3 = *(const float4*)(xrow + 32 + g2 * 8 + 4);
  STAGE_W1(0, pool);
  __syncthreads();

#pragma unroll 1
  for (int t = 0; t < 8; ++t) {
    float4 xn0, xn1, xn2, xn3;
    if (t < 7) {
      STAGE_W1(t + 1, pool + ((t + 1) & 1) * 28672);  // in flight during MFMA
      const float* xr2 = xrow + (t + 1) * 64 + g2 * 8;
      xn0 = *(const float4*)xr2;
      xn1 = *(const float4*)(xr2 + 4);
      xn2 = *(const float4*)(xr2 + 32);
      xn3 = *(const float4*)(xr2 + 36);
    }
    const char* wbr = pool + (t & 1) * 28672;
#pragma unroll
    for (int kh = 0; kh < 2; ++kh) {
      const int d0 = t * 64 + kh * 32 + g2 * 8;
      const float4 xv0 = kh ? xc2 : xc0;
      const float4 xv1 = kh ? xc3 : xc1;
      const float4 gg0 = *(const float4*)&lnGs[d0];
      const float4 gg1 = *(const float4*)&lnGs[d0 + 4];
      const float4 bb0 = *(const float4*)&lnBs[d0];
      const float4 bb1 = *(const float4*)&lnBs[d0 + 4];
      float y0 = fmaf(fmaf(xv0.x, iv, nmuiv), gg0.x, bb0.x);
      float y1 = fmaf(fmaf(xv0.y, iv, nmuiv), gg0.y, bb0.y);
      float y2 = fmaf(fmaf(xv0.z, iv, nmuiv), gg0.z, bb0.z);
      float y3 = fmaf(fmaf(xv0.w, iv, nmuiv), gg0.w, bb0.w);
      float y4 = fmaf(fmaf(xv1.x, iv, nmuiv), gg1.x, bb1.x);
      float y5 = fmaf(fmaf(xv1.y, iv, nmuiv), gg1.y, bb1.y);
      float y6 = fmaf(fmaf(xv1.z, iv, nmuiv), gg1.z, bb1.z);
      float y7 = fmaf(fmaf(xv1.w, iv, nmuiv), gg1.w, bb1.w);
      u32 h01 = cvtpk(y0, y1), h23 = cvtpk(y2, y3);
      u32 h45 = cvtpk(y4, y5), h67 = cvtpk(y6, y7);
      u32 l01 = cvtpk(y0 - flo16(h01), y1 - fhi16(h01));
      u32 l23 = cvtpk(y2 - flo16(h23), y3 - fhi16(h23));
      u32 l45 = cvtpk(y4 - flo16(h45), y5 - fhi16(h45));
      u32 l67 = cvtpk(y6 - flo16(h67), y7 - fhi16(h67));
      const s16x8 fh = mkfrag4(h01, h23, h45, h67);
      const s16x8 fl = mkfrag4(l01, l23, l45, l67);
      const int bA = kh ? bA1 : bA0;
#pragma unroll
      for (int n = 0; n < 7; ++n) {
        const s16x8 bh = *(const s16x8*)(wbr + n * 2048 + bA);
        const s16x8 bl = *(const s16x8*)(wbr + 14336 + n * 2048 + bA);
        acc1[n] = MFMA16(fh, bh, acc1[n]);
        acc1[n] = MFMA16(fl, bh, acc1[n]);
        acc1[n] = MFMA16(fh, bl, acc1[n]);
      }
    }
    __syncthreads();  // drains stage loads (vmcnt0) + guards buffer swap
    if (t < 7) { xc0 = xn0; xc1 = xn1; xc2 = xn2; xc3 = xn3; }
  }

  // ======== stage W2 tiles; bias + exact GELU -> h bf16 swz in SEL ========
  char* W2b = pool + 32768;
  {
#pragma unroll
    for (int i = 0; i < 4; ++i) {
      const int j2 = w + 8 * i;  // 0..31
      const int part = (j2 >= 16);
      const int jj = j2 - part * 16;
      const int s = jj * 64 + lane;
      const int row = s >> 4, uu = s & 15;
      const u16* src = (part ? w2tl : w2th) + row * 128 + ((uu ^ (row & 15)) << 3);
      GLOAD16(src, W2b + part * 16384 + jj * 1024);
    }
  }
#pragma unroll
  for (int n = 0; n < 7; ++n) {
    const int col = 16 * n + cl;
    const float bia = b1s[col];
#pragma unroll
    for (int r = 0; r < 4; ++r) {
      const int row = 16 * w + 4 * g2 + r;
      float v = acc1[n][r] + bia;
      float ge = 0.5f * v * (1.f + erff(v * 0.70710678118f));
      const int byteoff = (row * 256 + col * 2) ^ ((row & 7) << 4);
      *(u16*)(pool + byteoff) = f2bf(ge);
    }
  }
  for (int i = tid; i < 1024; i += 512) {  // zero pad cols 112..127
    const int row = i >> 3;
    const int col = 112 + 2 * (i & 7);
    const int byteoff = (row * 256 + col * 2) ^ ((row & 7) << 4);
    *(u32*)(pool + byteoff) = 0u;
  }
  __syncthreads();

  // ================= mm2: logits[128][64] = h @ W2T^T =================
  f32x4 acc2[4];
#pragma unroll
  for (int n = 0; n < 4; ++n) acc2[n] = (f32x4){0.f, 0.f, 0.f, 0.f};
  {
    const int row2 = 16 * w + cl;
#pragma unroll
    for (int kk = 0; kk < 4; ++kk) {
      const int byteoff = (row2 * 256 + kk * 64 + g2 * 16) ^ ((row2 & 7) << 4);
      const s16x8 ha = *(const s16x8*)(pool + byteoff);
      const int bB = cl * 256 + (((kk * 4 + g2) ^ cl) << 4);
#pragma unroll
      for (int n = 0; n < 4; ++n) {
        const s16x8 bh = *(const s16x8*)(W2b + n * 4096 + bB);
        const s16x8 bl = *(const s16x8*)(W2b + 16384 + n * 4096 + bB);
        acc2[n] = MFMA16(ha, bh, acc2[n]);
        acc2[n] = MFMA16(ha, bl, acc2[n]);
      }
    }
  }
  __syncthreads();  // all W2b/h reads done before wt overwrites the region
  float* wt = (float*)(pool + 32768);  // [64][132]
  {
    const float scv = sscale;
#pragma unroll
    for (int n = 0; n < 4; ++n) {
      const int p = 16 * n + cl;
#pragma unroll
      for (int r = 0; r < 4; ++r) {
        const int k = 16 * w + 4 * g2 + r;
        wt[p * 132 + k] = (acc2[n][r] + b2s[p]) * scv;
      }
    }
  }
  __syncthreads();

  // ---- softmax over k (128) for each p (8 waves) ----
  for (int p = w; p < PP; p += 8) {
    float v0 = wt[p * 132 + lane], v1 = wt[p * 132 + 64 + lane];
    float mx = fmaxf(v0, v1);
    for (int m = 32; m; m >>= 1) mx = fmaxf(mx, __shfl_xor(mx, m));
    float e0 = expf(v0 - mx), e1 = expf(v1 - mx);
    float s = e0 + e1;
    for (int m = 32; m; m >>= 1) s += __shfl_xor(s, m);
    float is = 1.f / s;
    wt[p * 132 + lane] = e0 * is;
    wt[p * 132 + 64 + lane] = e1 * is;
  }
  __syncthreads();

  // ===== aggr: out[p][c] = w[p][k] @ sel[k][c], 8 chunks of 64 cols =====
  const int mb = w >> 2;   // 0..1 -> rows 32*mb + {0..31}
  const int nsub = w & 3;  // 16-col tile within 64-col chunk

  // chunk staging geometry (constant per thread across chunks)
  const int c4g = tid & 15;
  const int k0 = tid >> 4;  // token-row base; k = k0 + 32*s
  const float* xcb = xb + 4 * c4g;
  const int tk0 = keeps[k0], tk1 = keeps[k0 + 32];
  const int tk2 = keeps[k0 + 64], tk3 = keeps[k0 + 96];
  const int base_b = (((c4g >> 2) * 2 + ((k0 >> 2) & 1)) << 9) +
                     ((k0 >> 3) << 7) + ((k0 & 3) << 5) + ((c4g & 3) << 3);

  // prefetch chunk 0 (latency hidden under A-frag build)
  float4 pv0 = *(const float4*)(xcb + (size_t)tk0 * DD);
  float4 pv1 = *(const float4*)(xcb + (size_t)tk1 * DD);
  float4 pv2 = *(const float4*)(xcb + (size_t)tk2 * DD);
  float4 pv3 = *(const float4*)(xcb + (size_t)tk3 * DD);

  s16x8 ah0[4], al0[4], ah1[4], al1[4];  // A-frags (w hi/lo), mi = 0,1
  {
    const int pr0 = 32 * mb + cl;
    const int pr1 = pr0 + 16;
#pragma unroll
    for (int kk = 0; kk < 4; ++kk) {
      f32x4 wa = *(const f32x4*)&wt[pr0 * 132 + kk * 32 + 8 * g2];
      f32x4 wb = *(const f32x4*)&wt[pr0 * 132 + kk * 32 + 8 * g2 + 4];
      u32 a0 = cvtpk(wa.x, wa.y), a1 = cvtpk(wa.z, wa.w);
      u32 a2 = cvtpk(wb.x, wb.y), a3 = cvtpk(wb.z, wb.w);
      ah0[kk] = mkfrag4(a0, a1, a2, a3);
      al0[kk] = mkfrag4(cvtpk(wa.x - flo16(a0), wa.y - fhi16(a0)),
                        cvtpk(wa.z - flo16(a1), wa.w - fhi16(a1)),
                        cvtpk(wb.x - flo16(a2), wb.y - fhi16(a2)),
                        cvtpk(wb.z - flo16(a3), wb.w - fhi16(a3)));
      f32x4 wc = *(const f32x4*)&wt[pr1 * 132 + kk * 32 + 8 * g2];
      f32x4 wd = *(const f32x4*)&wt[pr1 * 132 + kk * 32 + 8 * g2 + 4];
      u32 c0 = cvtpk(wc.x, wc.y), c1 = cvtpk(wc.z, wc.w);
      u32 c2 = cvtpk(wd.x, wd.y), c3 = cvtpk(wd.z, wd.w);
      ah1[kk] = mkfrag4(c0, c1, c2, c3);
      al1[kk] = mkfrag4(cvtpk(wc.x - flo16(c0), wc.y - fhi16(c0)),
                        cvtpk(wc.z - flo16(c1), wc.w - fhi16(c1)),
                        cvtpk(wd.x - flo16(c2), wd.y - fhi16(c2)),
                        cvtpk(wd.z - flo16(c3), wd.w - fhi16(c3)));
    }
  }
  const u32 trbase = (u32)(size_t)pool + nsub * 1024 + g2 * 128 + 8 * cl;

#define SELW(v, bo)                                                            \
  {                                                                            \
    u32 h01_ = cvtpk((v).x, (v).y), h23_ = cvtpk((v).z, (v).w);                \
    u32 q01_ = cvtpk((v).x - flo16(h01_), (v).y - fhi16(h01_));                \
    u32 q23_ = cvtpk((v).z - flo16(h23_), (v).w - fhi16(h23_));                \
    *(u64*)(pool + (bo)) = ((u64)h23_ << 32) | h01_;                           \
    *(u64*)(pool + 16384 + (bo)) = ((u64)q23_ << 32) | q01_;                   \
  }

#pragma unroll 1
  for (int ch = 0; ch < 8; ++ch) {
    SELW(pv0, base_b);
    SELW(pv1, base_b + 4096);
    SELW(pv2, base_b + 8192);
    SELW(pv3, base_b + 12288);
    __syncthreads();
    float4 nv0, nv1, nv2, nv3;
    if (ch < 7) {  // prefetch next chunk; hides gather latency under MFMA
      const float* xnp = xcb + (ch + 1) * 64;
      nv0 = *(const float4*)(xnp + (size_t)tk0 * DD);
      nv1 = *(const float4*)(xnp + (size_t)tk1 * DD);
      nv2 = *(const float4*)(xnp + (size_t)tk2 * DD);
      nv3 = *(const float4*)(xnp + (size_t)tk3 * DD);
    }
    f32x4 acg0 = (f32x4){0.f, 0.f, 0.f, 0.f};
    f32x4 acg1 = (f32x4){0.f, 0.f, 0.f, 0.f};
    u64 th[4][2], tl[4][2];
#pragma unroll
    for (int kk = 0; kk < 4; ++kk) {
      th[kk][0] = trread(trbase, kk * 4096);
      th[kk][1] = trread(trbase, kk * 4096 + 512);
      tl[kk][0] = trread(trbase, kk * 4096 + 16384);
      tl[kk][1] = trread(trbase, kk * 4096 + 16896);
    }
    asm volatile("s_waitcnt lgkmcnt(0)" ::: "memory");
    __builtin_amdgcn_sched_barrier(0);
#pragma unroll
    for (int kk = 0; kk < 4; ++kk) {
      const s16x8 bh = mkfrag2(th[kk][0], th[kk][1]);
      const s16x8 bl = mkfrag2(tl[kk][0], tl[kk][1]);
      acg0 = MFMA16(ah0[kk], bh, acg0);
      acg0 = MFMA16(al0[kk], bh, acg0);
      acg0 = MFMA16(ah0[kk], bl, acg0);
      acg1 = MFMA16(ah1[kk], bh, acg1);
      acg1 = MFMA16(al1[kk], bh, acg1);
      acg1 = MFMA16(ah1[kk], bl, acg1);
    }
    const int ccol = ch * 64 + 16 * nsub + cl;
#pragma unroll
    for (int r = 0; r < 4; ++r) {
      const int p0 = 32 * mb + 4 * g2 + r;
      if (p0 < PP) out[((size_t)b * 52 + p0) * DD + ccol] = acg0[r];
      const int p1 = 32 * mb + 16 + 4 * g2 + r;
      if (p1 < PP) out[((size_t)b * 52 + p1) * DD + ccol] = acg1[r];
    }
    __syncthreads();
    if (ch < 7) { pv0 = nv0; pv1 = nv1; pv2 = nv2; pv3 = nv3; }
  }
}

extern "C" void kernel_launch(void* const* d_in, const int* in_sizes, int n_in,
                              void* d_out, int out_size, void* d_ws, size_t ws_size,
                              hipStream_t stream) {
  const float* x = (const float*)d_in[0];
  const float* ca = (const float*)d_in[1];
  const float* lng = (const float*)d_in[2];
  const float* lnb = (const float*)d_in[3];
  const float* w1 = (const float*)d_in[4];
  const float* b1 = (const float*)d_in[5];
  const float* w2 = (const float*)d_in[6];
  const float* b2 = (const float*)d_in[7];
  const float* scale = (const float*)d_in[8];
  float* out = (float*)d_out;

  char* ws = (char*)d_ws;
  int* keepg = (int*)ws;               // 512*128*4 = 262144
  float* muk = (float*)(ws + 262144);  // 262144
  float* ivk = (float*)(ws + 524288);  // 262144
  u16* w1th = (u16*)(ws + 786432);     // 114688
  u16* w1tl = (u16*)(ws + 901120);     // 114688
  u16* w2th = (u16*)(ws + 1015808);    // 16384
  u16* w2tl = (u16*)(ws + 1032192);    // 16384 -> total 1 MB

  k_score<<<BB + 16, 1024, 0, stream>>>(x, ca, w1, w2, out, keepg, muk, ivk,
                                        w1th, w1tl, w2th, w2tl);
  k_fused<<<BB, 512, 0, stream>>>(x, w1th, w1tl, w2th, w2tl, lng, lnb, b1, b2,
                                  scale, keepg, muk, ivk, out);
}

// Round 3
// 490.040 us; speedup vs baseline: 1.3910x; 1.0677x over previous
//
#include <hip/hip_runtime.h>

#define BB 512
#define TT 256
#define DD 512
#define HH 102
#define PP 51
#define NKEEP 128

typedef unsigned short u16;
typedef unsigned int u32;
typedef unsigned long long u64;
typedef float f32x4 __attribute__((ext_vector_type(4)));
typedef short s16x8 __attribute__((ext_vector_type(8)));

#define MFMA16(A, B, C) __builtin_amdgcn_mfma_f32_16x16x32_bf16((A), (B), (C), 0, 0, 0)

// async global->LDS, 16B per lane, dest = uniform base + lane*16
#define GLOAD16(gsrc, ldst)                                                     \
  __builtin_amdgcn_global_load_lds(                                             \
      (const __attribute__((address_space(1))) u32*)(gsrc),                     \
      (__attribute__((address_space(3))) u32*)(ldst), 16, 0, 0)

static __device__ __forceinline__ float bf2f(u16 u) {
  u32 v = ((u32)u) << 16;
  float f;
  __builtin_memcpy(&f, &v, 4);
  return f;
}
static __device__ __forceinline__ u16 f2bf(float f) {
  u32 v;
  __builtin_memcpy(&v, &f, 4);
  u32 r = v + 0x7fffu + ((v >> 16) & 1u);
  return (u16)(r >> 16);
}
// v_cvt_pk_bf16_f32: dst.lo = bf16(a), dst.hi = bf16(b)  (no builtin on gfx950)
static __device__ __forceinline__ u32 cvtpk(float a, float b) {
  u32 r;
  asm("v_cvt_pk_bf16_f32 %0, %1, %2" : "=v"(r) : "v"(a), "v"(b));
  return r;
}
static __device__ __forceinline__ float flo16(u32 u) {
  u32 v = u << 16;
  float f;
  __builtin_memcpy(&f, &v, 4);
  return f;
}
static __device__ __forceinline__ float fhi16(u32 u) {
  u32 v = u & 0xffff0000u;
  float f;
  __builtin_memcpy(&f, &v, 4);
  return f;
}
static __device__ __forceinline__ s16x8 mkfrag4(u32 a, u32 b, u32 c, u32 d) {
  u32 t[4] = {a, b, c, d};
  s16x8 f;
  __builtin_memcpy(&f, t, 16);
  return f;
}
static __device__ __forceinline__ s16x8 mkfrag2(u64 a, u64 b) {
  u64 t[2] = {a, b};
  s16x8 f;
  __builtin_memcpy(&f, t, 16);
  return f;
}
static __device__ __forceinline__ u64 trread(u32 addr, int imm) {
  u64 d;
  asm volatile("ds_read_b64_tr_b16 %0, %1 offset:%2" : "=v"(d) : "v"(addr), "i"(imm));
  return d;
}

// ---------------- Kernel 1: scores, sort, non-softmax, extra row, LN stats ----
// SINGLE PASS over x: per 64-col chunk, the column-sum c[chunk] is computed
// from the chunk itself, so dot(x_t, c) = sum_chunks dot(x_t[ch], c[ch]) needs
// x only once (registers), all in exact fp32.
// blocks >= BB: weight prep (bf16 hi/lo transposed W1, W2 into workspace)
__global__ __launch_bounds__(1024, 8) void k_score(
    const float* __restrict__ x, const float* __restrict__ ca,
    const float* __restrict__ w1, const float* __restrict__ w2,
    float* __restrict__ out, int* __restrict__ keepg,
    float* __restrict__ muk, float* __restrict__ ivk,
    u16* __restrict__ w1th, u16* __restrict__ w1tl,
    u16* __restrict__ w2th, u16* __restrict__ w2tl) {
  const int tid = threadIdx.x;

  if (blockIdx.x >= BB) {  // ---- weight prep: 16 blocks x 4096 elems ----
    const int e0 = (blockIdx.x - BB) * 4096;
#pragma unroll
    for (int i = 0; i < 4; ++i) {
      const int e = e0 + i * 1024 + tid;
      if (e < 57344) {  // W1T[112][512] = W1[k][p] pad p->112
        const int p = e >> 9, k = e & 511;
        const float v = (p < HH) ? w1[(size_t)k * HH + p] : 0.f;
        const u16 hi = f2bf(v);
        w1th[e] = hi;
        w1tl[e] = f2bf(v - bf2f(hi));
      } else {  // W2T[64][128] = W2[j][p] pad p->64, j->128
        const int e2 = e - 57344;
        const int p = e2 >> 7, j = e2 & 127;
        const float v = (p < PP && j < HH) ? w2[(size_t)j * PP + p] : 0.f;
        const u16 hi = f2bf(v);
        w2th[e2] = hi;
        w2tl[e2] = f2bf(v - bf2f(hi));
      }
    }
    return;
  }

  __shared__ __align__(16) float xls[256 * 64];  // 64 KB; aliased: pc (P3), part5 (P5)
  __shared__ float part2[1024];                  // col-reduce stage; aliased: mls/ils
  __shared__ float cs[64];                       // chunk colsum (fp32); cs[0] reused for inv
  __shared__ float ctot[512];                    // full colsum (for ||c||)
  __shared__ float sc[TT];
  __shared__ float ss[TT];
  __shared__ int perm[TT];
  __shared__ float wq[NKEEP];
  __shared__ float red[128];

  int* pc = (int*)xls;
  float* part5 = xls;
  float* mls = part2;
  float* ils = part2 + 256;

  const int b = blockIdx.x;
  const float* xb = x + (size_t)b * TT * DD;

  // ---- phase 1+2 fused: one pass, 8 chunks of 64 cols ----
  const int r = tid >> 2;   // token row 0..255
  const int q = tid & 3;    // 16-col segment within chunk
  const int r7 = r & 7;
  const int rgA = tid >> 6, jA = tid & 63;  // stage-A mapping (rg wave-uniform)
  const int uA = jA >> 2, sA = jA & 3;

  float s1p = 0.f, s2p = 0.f, dtp = 0.f;

#pragma unroll 1
  for (int ch = 0; ch < 8; ++ch) {
    // step 1: load 16 x values (fp32, registers), row stats, swizzled LDS stage
    const float* xp = xb + (size_t)r * DD + ch * 64 + q * 16;
    const float4 v0 = *(const float4*)xp;
    const float4 v1 = *(const float4*)(xp + 4);
    const float4 v2 = *(const float4*)(xp + 8);
    const float4 v3 = *(const float4*)(xp + 12);
    s1p += (v0.x + v0.y + v0.z + v0.w) + (v1.x + v1.y + v1.z + v1.w) +
           (v2.x + v2.y + v2.z + v2.w) + (v3.x + v3.y + v3.z + v3.w);
    s2p += v0.x * v0.x + v0.y * v0.y + v0.z * v0.z + v0.w * v0.w +
           v1.x * v1.x + v1.y * v1.y + v1.z * v1.z + v1.w * v1.w +
           v2.x * v2.x + v2.y * v2.y + v2.z * v2.z + v2.w * v2.w +
           v3.x * v3.x + v3.y * v3.y + v3.z * v3.z + v3.w * v3.w;
    // unit u = q*4+k, stored at float offset r*64 + ((u^(r&7))<<2)
    *(float4*)&xls[r * 64 + (((q * 4 + 0) ^ r7) << 2)] = v0;
    *(float4*)&xls[r * 64 + (((q * 4 + 1) ^ r7) << 2)] = v1;
    *(float4*)&xls[r * 64 + (((q * 4 + 2) ^ r7) << 2)] = v2;
    *(float4*)&xls[r * 64 + (((q * 4 + 3) ^ r7) << 2)] = v3;
    __syncthreads();
    // step 2: column partial sums, 16 rows per (wave, col)
    {
      float a = 0.f;
#pragma unroll
      for (int rr = 0; rr < 16; ++rr) {
        a += xls[(rgA * 16 + rr) * 64 + ((uA ^ (rr & 7)) << 2) + sA];
      }
      part2[rgA * 64 + jA] = a;
    }
    __syncthreads();
    // step 3: final column sum for this chunk
    if (tid < 64) {
      float c = 0.f;
#pragma unroll
      for (int g = 0; g < 16; ++g) c += part2[g * 64 + tid];
      cs[tid] = c;
      ctot[ch * 64 + tid] = c;
    }
    __syncthreads();
    // step 4: dot partial from registers (overlaps next chunk's loads)
    {
      const float4 c0 = *(const float4*)&cs[q * 16];
      const float4 c1 = *(const float4*)&cs[q * 16 + 4];
      const float4 c2 = *(const float4*)&cs[q * 16 + 8];
      const float4 c3 = *(const float4*)&cs[q * 16 + 12];
      dtp += v0.x * c0.x + v0.y * c0.y + v0.z * c0.z + v0.w * c0.w +
             v1.x * c1.x + v1.y * c1.y + v1.z * c1.z + v1.w * c1.w +
             v2.x * c2.x + v2.y * c2.y + v2.z * c2.z + v2.w * c2.w +
             v3.x * c3.x + v3.y * c3.y + v3.z * c3.z + v3.w * c3.w;
    }
  }
  __syncthreads();

  // ---- ||mean|| and inverse (common factor -> rank-order safe) ----
  if (tid < 512) {
    float cv = ctot[tid];
    float v = cv * cv;
    for (int m = 32; m; m >>= 1) v += __shfl_xor(v, m);
    if ((tid & 63) == 0) red[tid >> 6] = v;
  }
  __syncthreads();
  if (tid == 0) {
    float cn2 = red[0] + red[1] + red[2] + red[3] + red[4] + red[5] + red[6] + red[7];
    cs[0] = 1.f / fmaxf(sqrtf(cn2) * (1.f / 256.f), 1e-12f);
  }
  __syncthreads();

  // ---- per-row finalize: score + LN stats ----
  {
    float a1 = s1p, a2 = s2p, ad = dtp;
    a1 += __shfl_xor(a1, 1); a1 += __shfl_xor(a1, 2);
    a2 += __shfl_xor(a2, 1); a2 += __shfl_xor(a2, 2);
    ad += __shfl_xor(ad, 1); ad += __shfl_xor(ad, 2);
    if (q == 0) {
      const float invc = cs[0];
      const float self = ad * (1.f / 256.f) * invc;
      sc[r] = self / fmaxf(sqrtf(a2), 1e-12f) + ca[b * TT + r];
      const float mu = a1 * (1.f / DD);
      const float var = a2 * (1.f / DD) - mu * mu;
      mls[r] = mu;
      ils[r] = rsqrtf(var + 1e-5f);
    }
  }
  __syncthreads();

  // phase 3: stable descending rank, distributed over 4 j-chunks
  {
    int t = tid & 255, chh = tid >> 8;
    float st = sc[t];
    int cnt = 0;
    for (int j = chh * 64; j < chh * 64 + 64; ++j) {
      float sj = sc[j];
      cnt += (sj > st) || (sj == st && j < t);
    }
    pc[chh * 256 + t] = cnt;
  }
  __syncthreads();
  if (tid < 256) {
    int rank = pc[tid] + pc[256 + tid] + pc[512 + tid] + pc[768 + tid];
    perm[rank] = tid;
    ss[rank] = sc[tid];
  }
  __syncthreads();

  // phase 4: softmax over non-kept (sorted 128..255); max = ss[128] (sorted)
  if (tid < 128) {
    float e = expf(ss[NKEEP + tid] - ss[NKEEP]);
    wq[tid] = e;
    red[tid] = e;
  }
  __syncthreads();
  for (int s = 64; s > 0; s >>= 1) {
    if (tid < s) red[tid] += red[tid + s];
    __syncthreads();
  }
  if (tid < 128) {
    wq[tid] *= (1.f / red[0]);
    const int pm = perm[tid];
    keepg[b * NKEEP + tid] = pm;
    muk[b * NKEEP + tid] = mls[pm];
    ivk[b * NKEEP + tid] = ils[pm];
  }
  __syncthreads();

  // phase 5: extra = sum(non * w) -> out row 51 (8-way token-split)
  {
    int c4 = (tid & 127) * 4, tg = tid >> 7;
    float4 a = {0.f, 0.f, 0.f, 0.f};
    for (int qq = tg * 16; qq < tg * 16 + 16; ++qq) {
      int tok = perm[NKEEP + qq] & 255;
      float w = wq[qq];
      float4 v = *(const float4*)(xb + tok * DD + c4);
      a.x += w * v.x; a.y += w * v.y; a.z += w * v.z; a.w += w * v.w;
    }
    *(float4*)&part5[tg * 512 + c4] = a;
  }
  __syncthreads();
  if (tid < 128) {
    int c4 = tid * 4;
    float4 m = {0.f, 0.f, 0.f, 0.f};
    for (int g = 0; g < 8; ++g) {
      float4 v = *(const float4*)&part5[g * 512 + c4];
      m.x += v.x; m.y += v.y; m.z += v.z; m.w += v.w;
    }
    *(float4*)(out + ((size_t)b * 52 + 51) * DD + c4) = m;
  }
}

// ------ Kernel 2 (MFMA): LN -> GEMM1 -> GELU -> GEMM2 -> softmax -> aggr ----
// LDS pool phases:
//  mm1 : WB[2] double-buffer @0, each 28672 B (W1T tile hi 14336 | lo 14336)
//  mm2 : SEL h-tile [128][128]bf16 swz @0 (32768) | W2 tiles @32768 (hi16K|lo16K)
//  aggr: SEL tr-tiles hi @0 / lo @16384 | wt[64][132] f32 @32768 (33792)
__global__ __launch_bounds__(512, 2) void k_fused(
    const float* __restrict__ x,
    const u16* __restrict__ w1th, const u16* __restrict__ w1tl,
    const u16* __restrict__ w2th, const u16* __restrict__ w2tl,
    const float* __restrict__ lng, const float* __restrict__ lnb,
    const float* __restrict__ b1, const float* __restrict__ b2,
    const float* __restrict__ scale, const int* __restrict__ keepg,
    const float* __restrict__ mukg, const float* __restrict__ ivkg,
    float* __restrict__ out) {
  __shared__ __align__(16) char pool[66560];
  __shared__ __align__(16) float lnGs[DD], lnBs[DD];
  __shared__ float mus[NKEEP], ivs[NKEEP];
  __shared__ int keeps[NKEEP];
  __shared__ float b1s[112], b2s[64];
  __shared__ float sscale;

  const int b = blockIdx.x;
  const int tid = threadIdx.x;
  const int w = tid >> 6;    // wave 0..7
  const int lane = tid & 63;
  const int cl = lane & 15;  // 16-lane column index
  const int g2 = lane >> 4;  // quarter-group 0..3

  if (tid < NKEEP) {
    keeps[tid] = keepg[b * NKEEP + tid] & 255;
    mus[tid] = mukg[b * NKEEP + tid];
    ivs[tid] = ivkg[b * NKEEP + tid];
  }
  for (int i = tid; i < DD; i += 512) {
    lnGs[i] = lng[i];
    lnBs[i] = lnb[i];
  }
  if (tid < 112) b1s[tid] = (tid < HH) ? b1[tid] : 0.f;
  if (tid < 64) b2s[tid] = (tid < PP) ? b2[tid] : 0.f;
  if (tid == 0) sscale = scale[0];
  __syncthreads();

  const float* xb = x + (size_t)b * TT * DD;

  // ================= mm1: h[128][112] = LN(sel) @ W1 =================
  const int rowm = 16 * w + cl;
  const int tok = keeps[rowm];
  const float mu = mus[rowm], iv = ivs[rowm];
  const float nmuiv = -mu * iv;
  const float* xrow = xb + (size_t)tok * DD;

  // per-thread swizzled LDS byte offsets for B-frag reads (row = n*16+cl):
  // byte = n*2048 + cl*128 + ((kh*4+g2)^(cl&7))*16   (+14336 for lo)
  const int swz7 = cl & 7;
  const int bA0 = cl * 128 + ((g2 ^ swz7) << 4);
  const int bA1 = cl * 128 + (((4 + g2) ^ swz7) << 4);

  f32x4 acc1[7];
#pragma unroll
  for (int n = 0; n < 7; ++n) acc1[n] = (f32x4){0.f, 0.f, 0.f, 0.f};

  // stage W1T tile tt (hi+lo 28672 B) into dst; source pre-swizzled so the
  // linear LDS slot (row,u) holds global unit u^(row&7)  [m173 pattern]
#define STAGE_W1(tt, dst)                                                      \
  {                                                                            \
    _Pragma("unroll") for (int i_ = 0; i_ < 4; ++i_) {                         \
      const int j_ = w + 8 * i_;                                               \
      if (j_ < 28) {                                                           \
        const int s_ = j_ * 64 + lane;                                         \
        const int part_ = (j_ >= 14);                                          \
        const int sr_ = s_ - part_ * 896;                                      \
        const int row_ = sr_ >> 3, uu_ = sr_ & 7;                              \
        const u16* src_ = (part_ ? w1tl : w1th) + row_ * 512 + (tt)*64 +       \
                          ((uu_ ^ (row_ & 7)) << 3);                           \
        GLOAD16(src_, (dst) + j_ * 1024);                                      \
      }                                                                        \
    }                                                                          \
  }

  float4 xc0 = *(const float4*)(xrow + g2 * 8);
  float4 xc1 = *(const float4*)(xrow + g2 * 8 + 4);
  float4 xc2 = *(const float4*)(xrow + 32 + g2 * 8);
  float4 xc3 = *(const float4*)(xrow + 32 + g2 * 8 + 4);
  STAGE_W1(0, pool);
  __syncthreads();

#pragma unroll 1
  for (int t = 0; t < 8; ++t) {
    float4 xn0, xn1, xn2, xn3;
    if (t < 7) {
      STAGE_W1(t + 1, pool + ((t + 1) & 1) * 28672);  // in flight during MFMA
      const float* xr2 = xrow + (t + 1) * 64 + g2 * 8;
      xn0 = *(const float4*)xr2;
      xn1 = *(const float4*)(xr2 + 4);
      xn2 = *(const float4*)(xr2 + 32);
      xn3 = *(const float4*)(xr2 + 36);
    }
    const char* wbr = pool + (t & 1) * 28672;
#pragma unroll
    for (int kh = 0; kh < 2; ++kh) {
      const int d0 = t * 64 + kh * 32 + g2 * 8;
      const float4 xv0 = kh ? xc2 : xc0;
      const float4 xv1 = kh ? xc3 : xc1;
      const float4 gg0 = *(const float4*)&lnGs[d0];
      const float4 gg1 = *(const float4*)&lnGs[d0 + 4];
      const float4 bb0 = *(const float4*)&lnBs[d0];
      const float4 bb1 = *(const float4*)&lnBs[d0 + 4];
      float y0 = fmaf(fmaf(xv0.x, iv, nmuiv), gg0.x, bb0.x);
      float y1 = fmaf(fmaf(xv0.y, iv, nmuiv), gg0.y, bb0.y);
      float y2 = fmaf(fmaf(xv0.z, iv, nmuiv), gg0.z, bb0.z);
      float y3 = fmaf(fmaf(xv0.w, iv, nmuiv), gg0.w, bb0.w);
      float y4 = fmaf(fmaf(xv1.x, iv, nmuiv), gg1.x, bb1.x);
      float y5 = fmaf(fmaf(xv1.y, iv, nmuiv), gg1.y, bb1.y);
      float y6 = fmaf(fmaf(xv1.z, iv, nmuiv), gg1.z, bb1.z);
      float y7 = fmaf(fmaf(xv1.w, iv, nmuiv), gg1.w, bb1.w);
      u32 h01 = cvtpk(y0, y1), h23 = cvtpk(y2, y3);
      u32 h45 = cvtpk(y4, y5), h67 = cvtpk(y6, y7);
      u32 l01 = cvtpk(y0 - flo16(h01), y1 - fhi16(h01));
      u32 l23 = cvtpk(y2 - flo16(h23), y3 - fhi16(h23));
      u32 l45 = cvtpk(y4 - flo16(h45), y5 - fhi16(h45));
      u32 l67 = cvtpk(y6 - flo16(h67), y7 - fhi16(h67));
      const s16x8 fh = mkfrag4(h01, h23, h45, h67);
      const s16x8 fl = mkfrag4(l01, l23, l45, l67);
      const int bA = kh ? bA1 : bA0;
#pragma unroll
      for (int n = 0; n < 7; ++n) {
        const s16x8 bh = *(const s16x8*)(wbr + n * 2048 + bA);
        const s16x8 bl = *(const s16x8*)(wbr + 14336 + n * 2048 + bA);
        acc1[n] = MFMA16(fh, bh, acc1[n]);
        acc1[n] = MFMA16(fl, bh, acc1[n]);
        acc1[n] = MFMA16(fh, bl, acc1[n]);
      }
    }
    __syncthreads();  // drains stage loads (vmcnt0) + guards buffer swap
    if (t < 7) { xc0 = xn0; xc1 = xn1; xc2 = xn2; xc3 = xn3; }
  }

  // ======== stage W2 tiles; bias + exact GELU -> h bf16 swz in SEL ========
  char* W2b = pool + 32768;
  {
#pragma unroll
    for (int i = 0; i < 4; ++i) {
      const int j2 = w + 8 * i;  // 0..31
      const int part = (j2 >= 16);
      const int jj = j2 - part * 16;
      const int s = jj * 64 + lane;
      const int row = s >> 4, uu = s & 15;
      const u16* src = (part ? w2tl : w2th) + row * 128 + ((uu ^ (row & 15)) << 3);
      GLOAD16(src, W2b + part * 16384 + jj * 1024);
    }
  }
#pragma unroll
  for (int n = 0; n < 7; ++n) {
    const int col = 16 * n + cl;
    const float bia = b1s[col];
#pragma unroll
    for (int r = 0; r < 4; ++r) {
      const int row = 16 * w + 4 * g2 + r;
      float v = acc1[n][r] + bia;
      float ge = 0.5f * v * (1.f + erff(v * 0.70710678118f));
      const int byteoff = (row * 256 + col * 2) ^ ((row & 7) << 4);
      *(u16*)(pool + byteoff) = f2bf(ge);
    }
  }
  for (int i = tid; i < 1024; i += 512) {  // zero pad cols 112..127
    const int row = i >> 3;
    const int col = 112 + 2 * (i & 7);
    const int byteoff = (row * 256 + col * 2) ^ ((row & 7) << 4);
    *(u32*)(pool + byteoff) = 0u;
  }
  __syncthreads();

  // ================= mm2: logits[128][64] = h @ W2T^T =================
  f32x4 acc2[4];
#pragma unroll
  for (int n = 0; n < 4; ++n) acc2[n] = (f32x4){0.f, 0.f, 0.f, 0.f};
  {
    const int row2 = 16 * w + cl;
#pragma unroll
    for (int kk = 0; kk < 4; ++kk) {
      const int byteoff = (row2 * 256 + kk * 64 + g2 * 16) ^ ((row2 & 7) << 4);
      const s16x8 ha = *(const s16x8*)(pool + byteoff);
      const int bB = cl * 256 + (((kk * 4 + g2) ^ cl) << 4);
#pragma unroll
      for (int n = 0; n < 4; ++n) {
        const s16x8 bh = *(const s16x8*)(W2b + n * 4096 + bB);
        const s16x8 bl = *(const s16x8*)(W2b + 16384 + n * 4096 + bB);
        acc2[n] = MFMA16(ha, bh, acc2[n]);
        acc2[n] = MFMA16(ha, bl, acc2[n]);
      }
    }
  }
  __syncthreads();  // all W2b/h reads done before wt overwrites the region
  float* wt = (float*)(pool + 32768);  // [64][132]
  {
    const float scv = sscale;
#pragma unroll
    for (int n = 0; n < 4; ++n) {
      const int p = 16 * n + cl;
#pragma unroll
      for (int r = 0; r < 4; ++r) {
        const int k = 16 * w + 4 * g2 + r;
        wt[p * 132 + k] = (acc2[n][r] + b2s[p]) * scv;
      }
    }
  }
  __syncthreads();

  // ---- softmax over k (128) for each p (8 waves) ----
  for (int p = w; p < PP; p += 8) {
    float v0 = wt[p * 132 + lane], v1 = wt[p * 132 + 64 + lane];
    float mx = fmaxf(v0, v1);
    for (int m = 32; m; m >>= 1) mx = fmaxf(mx, __shfl_xor(mx, m));
    float e0 = expf(v0 - mx), e1 = expf(v1 - mx);
    float s = e0 + e1;
    for (int m = 32; m; m >>= 1) s += __shfl_xor(s, m);
    float is = 1.f / s;
    wt[p * 132 + lane] = e0 * is;
    wt[p * 132 + 64 + lane] = e1 * is;
  }
  __syncthreads();

  // ===== aggr: out[p][c] = w[p][k] @ sel[k][c], 8 chunks of 64 cols =====
  const int mb = w >> 2;   // 0..1 -> rows 32*mb + {0..31}
  const int nsub = w & 3;  // 16-col tile within 64-col chunk

  // chunk staging geometry (constant per thread across chunks)
  const int c4g = tid & 15;
  const int k0 = tid >> 4;  // token-row base; k = k0 + 32*s
  const float* xcb = xb + 4 * c4g;
  const int tk0 = keeps[k0], tk1 = keeps[k0 + 32];
  const int tk2 = keeps[k0 + 64], tk3 = keeps[k0 + 96];
  const int base_b = (((c4g >> 2) * 2 + ((k0 >> 2) & 1)) << 9) +
                     ((k0 >> 3) << 7) + ((k0 & 3) << 5) + ((c4g & 3) << 3);

  // prefetch chunk 0 (latency hidden under A-frag build)
  float4 pv0 = *(const float4*)(xcb + (size_t)tk0 * DD);
  float4 pv1 = *(const float4*)(xcb + (size_t)tk1 * DD);
  float4 pv2 = *(const float4*)(xcb + (size_t)tk2 * DD);
  float4 pv3 = *(const float4*)(xcb + (size_t)tk3 * DD);

  s16x8 ah0[4], al0[4], ah1[4], al1[4];  // A-frags (w hi/lo), mi = 0,1
  {
    const int pr0 = 32 * mb + cl;
    const int pr1 = pr0 + 16;
#pragma unroll
    for (int kk = 0; kk < 4; ++kk) {
      f32x4 wa = *(const f32x4*)&wt[pr0 * 132 + kk * 32 + 8 * g2];
      f32x4 wb = *(const f32x4*)&wt[pr0 * 132 + kk * 32 + 8 * g2 + 4];
      u32 a0 = cvtpk(wa.x, wa.y), a1 = cvtpk(wa.z, wa.w);
      u32 a2 = cvtpk(wb.x, wb.y), a3 = cvtpk(wb.z, wb.w);
      ah0[kk] = mkfrag4(a0, a1, a2, a3);
      al0[kk] = mkfrag4(cvtpk(wa.x - flo16(a0), wa.y - fhi16(a0)),
                        cvtpk(wa.z - flo16(a1), wa.w - fhi16(a1)),
                        cvtpk(wb.x - flo16(a2), wb.y - fhi16(a2)),
                        cvtpk(wb.z - flo16(a3), wb.w - fhi16(a3)));
      f32x4 wc = *(const f32x4*)&wt[pr1 * 132 + kk * 32 + 8 * g2];
      f32x4 wd = *(const f32x4*)&wt[pr1 * 132 + kk * 32 + 8 * g2 + 4];
      u32 c0 = cvtpk(wc.x, wc.y), c1 = cvtpk(wc.z, wc.w);
      u32 c2 = cvtpk(wd.x, wd.y), c3 = cvtpk(wd.z, wd.w);
      ah1[kk] = mkfrag4(c0, c1, c2, c3);
      al1[kk] = mkfrag4(cvtpk(wc.x - flo16(c0), wc.y - fhi16(c0)),
                        cvtpk(wc.z - flo16(c1), wc.w - fhi16(c1)),
                        cvtpk(wd.x - flo16(c2), wd.y - fhi16(c2)),
                        cvtpk(wd.z - flo16(c3), wd.w - fhi16(c3)));
    }
  }
  const u32 trbase = (u32)(size_t)pool + nsub * 1024 + g2 * 128 + 8 * cl;

#define SELW(v, bo)                                                            \
  {                                                                            \
    u32 h01_ = cvtpk((v).x, (v).y), h23_ = cvtpk((v).z, (v).w);                \
    u32 q01_ = cvtpk((v).x - flo16(h01_), (v).y - fhi16(h01_));                \
    u32 q23_ = cvtpk((v).z - flo16(h23_), (v).w - fhi16(h23_));                \
    *(u64*)(pool + (bo)) = ((u64)h23_ << 32) | h01_;                           \
    *(u64*)(pool + 16384 + (bo)) = ((u64)q23_ << 32) | q01_;                   \
  }

#pragma unroll 1
  for (int ch = 0; ch < 8; ++ch) {
    SELW(pv0, base_b);
    SELW(pv1, base_b + 4096);
    SELW(pv2, base_b + 8192);
    SELW(pv3, base_b + 12288);
    __syncthreads();
    float4 nv0, nv1, nv2, nv3;
    if (ch < 7) {  // prefetch next chunk; hides gather latency under MFMA
      const float* xnp = xcb + (ch + 1) * 64;
      nv0 = *(const float4*)(xnp + (size_t)tk0 * DD);
      nv1 = *(const float4*)(xnp + (size_t)tk1 * DD);
      nv2 = *(const float4*)(xnp + (size_t)tk2 * DD);
      nv3 = *(const float4*)(xnp + (size_t)tk3 * DD);
    }
    f32x4 acg0 = (f32x4){0.f, 0.f, 0.f, 0.f};
    f32x4 acg1 = (f32x4){0.f, 0.f, 0.f, 0.f};
    u64 th[4][2], tl[4][2];
#pragma unroll
    for (int kk = 0; kk < 4; ++kk) {
      th[kk][0] = trread(trbase, kk * 4096);
      th[kk][1] = trread(trbase, kk * 4096 + 512);
      tl[kk][0] = trread(trbase, kk * 4096 + 16384);
      tl[kk][1] = trread(trbase, kk * 4096 + 16896);
    }
    asm volatile("s_waitcnt lgkmcnt(0)" ::: "memory");
    __builtin_amdgcn_sched_barrier(0);
#pragma unroll
    for (int kk = 0; kk < 4; ++kk) {
      const s16x8 bh = mkfrag2(th[kk][0], th[kk][1]);
      const s16x8 bl = mkfrag2(tl[kk][0], tl[kk][1]);
      acg0 = MFMA16(ah0[kk], bh, acg0);
      acg0 = MFMA16(al0[kk], bh, acg0);
      acg0 = MFMA16(ah0[kk], bl, acg0);
      acg1 = MFMA16(ah1[kk], bh, acg1);
      acg1 = MFMA16(al1[kk], bh, acg1);
      acg1 = MFMA16(ah1[kk], bl, acg1);
    }
    const int ccol = ch * 64 + 16 * nsub + cl;
#pragma unroll
    for (int r = 0; r < 4; ++r) {
      const int p0 = 32 * mb + 4 * g2 + r;
      if (p0 < PP) out[((size_t)b * 52 + p0) * DD + ccol] = acg0[r];
      const int p1 = 32 * mb + 16 + 4 * g2 + r;
      if (p1 < PP) out[((size_t)b * 52 + p1) * DD + ccol] = acg1[r];
    }
    __syncthreads();
    if (ch < 7) { pv0 = nv0; pv1 = nv1; pv2 = nv2; pv3 = nv3; }
  }
}

extern "C" void kernel_launch(void* const* d_in, const int* in_sizes, int n_in,
                              void* d_out, int out_size, void* d_ws, size_t ws_size,
                              hipStream_t stream) {
  const float* x = (const float*)d_in[0];
  const float* ca = (const float*)d_in[1];
  const float* lng = (const float*)d_in[2];
  const float* lnb = (const float*)d_in[3];
  const float* w1 = (const float*)d_in[4];
  const float* b1 = (const float*)d_in[5];
  const float* w2 = (const float*)d_in[6];
  const float* b2 = (const float*)d_in[7];
  const float* scale = (const float*)d_in[8];
  float* out = (float*)d_out;

  char* ws = (char*)d_ws;
  int* keepg = (int*)ws;               // 512*128*4 = 262144
  float* muk = (float*)(ws + 262144);  // 262144
  float* ivk = (float*)(ws + 524288);  // 262144
  u16* w1th = (u16*)(ws + 786432);     // 114688
  u16* w1tl = (u16*)(ws + 901120);     // 114688
  u16* w2th = (u16*)(ws + 1015808);    // 16384
  u16* w2tl = (u16*)(ws + 1032192);    // 16384 -> total 1 MB

  k_score<<<BB + 16, 1024, 0, stream>>>(x, ca, w1, w2, out, keepg, muk, ivk,
                                        w1th, w1tl, w2th, w2tl);
  k_fused<<<BB, 512, 0, stream>>>(x, w1th, w1tl, w2th, w2tl, lng, lnb, b1, b2,
                                  scale, keepg, muk, ivk, out);
}